// Round 5
// baseline (214.799 us; speedup 1.0000x reference)
//
#include <hip/hip_runtime.h>
#include <hip/hip_bf16.h>

// ConvSelfAttentionModule: B=4, C=256, CQK=128, N=4096 (64x64), fp32 in/out.
// Pipeline (R5: NO materialized attention matrix):
//   k_wcvt   : W -> f16; q-weights/bias pre-scaled by log2(e) so exp -> exp2
//   k_xsplit : transpose x[b][c][n] -> xT[b][n][c] f16
//   k_proj   : f16 MFMA GEMM, K=256 single-shot glds staging -> qk, vv
//   k_sums   : S = q.k^T tiles (128x128), Z-partials = sum_j exp2(S) -> partial
//   k_rsum   : rowsum = sum partials
//   k_scalev : vv bf16 <- f16 vv / rowsum (softmax denom folded into V)
//   k_av2    : fused: recompute S per (i-chunk 64 x j-tile 64), P=exp2(S) bf16
//              -> LDS, AV MFMA (full C=256) accumulate over i, + residual.
//              K-frags in registers; q staged during AV phase, v during S phase.

typedef _Float16 f16;
typedef _Float16 f16x4v __attribute__((ext_vector_type(4)));
typedef _Float16 f16x8v __attribute__((ext_vector_type(8)));
typedef float f32x4v __attribute__((ext_vector_type(4)));
typedef unsigned short u16;
typedef unsigned short u16x4v __attribute__((ext_vector_type(4)));
typedef unsigned short u16x8v __attribute__((ext_vector_type(8)));
typedef short s16x8v __attribute__((ext_vector_type(8)));

static __device__ __forceinline__ f32x4v mfma16(f16x8v a, f16x8v b, f32x4v c) {
  // D[m][n]: a-frag m=lane&15,k=quad*8+j; b-frag (B^T rows) n=lane&15,k=quad*8+j;
  // D: col(n)=lane&15, row(m)=quad*4+reg
  return __builtin_amdgcn_mfma_f32_16x16x32_f16(a, b, c, 0, 0, 0);
}
static __device__ __forceinline__ f32x4v mfma_bf(s16x8v a, s16x8v b, f32x4v c) {
  return __builtin_amdgcn_mfma_f32_16x16x32_bf16(a, b, c, 0, 0, 0);
}
static __device__ __forceinline__ u16 f2bf(float f) {
  union { __hip_bfloat16 h; u16 u; } cv;
  cv.h = __float2bfloat16(f);  // RNE
  return cv.u;
}

#define AS1q __attribute__((address_space(1)))
#define AS3q __attribute__((address_space(3)))
static __device__ __forceinline__ void gl_lds16(const void* g, void* l) {
  // 16B per lane; LDS dest = wave-uniform base + lane*16 (per-lane global src OK)
  __builtin_amdgcn_global_load_lds((const AS1q unsigned int*)g,
                                   (AS3q unsigned int*)l, 16, 0, 0);
}

#define LOG2E 1.4426950408889634f

// ---------------- kernel 0a: weight convert ----------------
__global__ void k_wcvt(const float* __restrict__ wq, const float* __restrict__ bq,
                       const float* __restrict__ wk, const float* __restrict__ bk,
                       const float* __restrict__ wv, const float* __restrict__ bv,
                       f16* __restrict__ wh, float* __restrict__ bcat) {
  int o = blockIdx.x;          // 512 rows: 0-127 q (xlog2e), 128-255 k, 256-511 v
  int c = threadIdx.x;         // 256
  const float* wrow; float bias; float scale = 1.0f;
  if (o < 128)      { wrow = wq + (size_t)o * 256;         bias = bq[o]; scale = LOG2E; }
  else if (o < 256) { wrow = wk + (size_t)(o - 128) * 256; bias = bk[o - 128]; }
  else              { wrow = wv + (size_t)(o - 256) * 256; bias = bv[o - 256]; }
  wh[(size_t)o * 256 + c] = (f16)(wrow[c] * scale);
  if (c == 0) bcat[o] = bias * scale;
}

// ---------------- kernel 0b: x transpose ----------------
// x[b][c][n] f32 -> xT[b][n][c] f16
__global__ void k_xsplit(const float* __restrict__ x, f16* __restrict__ xh) {
  __shared__ float t[64][65];
  int b = blockIdx.z, c0 = blockIdx.y * 64, n0 = blockIdx.x * 64;
  int tx = threadIdx.x & 63, ty = threadIdx.x >> 6;
  const float* xb = x + ((size_t)b * 256 + c0) * 4096 + n0;
#pragma unroll
  for (int r = ty; r < 64; r += 4) t[r][tx] = xb[(size_t)r * 4096 + tx];
  __syncthreads();
  f16* dh = xh + ((size_t)b * 4096 + n0) * 256 + c0;
#pragma unroll
  for (int r = ty; r < 64; r += 4)
    dh[(size_t)r * 256 + tx] = (f16)t[tx][r];
}

// ---------------- kernel 1: projections (f16 NT GEMM, K=256 single-shot) ----------------
// D[i][o] = sum_c xT[i][c]*W[o][c] + b[o];  o<256 -> qk[b][i][o] ; else vv[b][o-256][i]
__global__ void __launch_bounds__(256, 2)
k_proj(const f16* __restrict__ xh, const f16* __restrict__ wh,
       const float* __restrict__ bcat, f16* __restrict__ qk, f16* __restrict__ vv) {
  extern __shared__ char smem[];   // 64KB
  int b = blockIdx.z, m0 = blockIdx.y * 64, n0 = blockIdx.x * 64;
  int tid = threadIdx.x, l = tid & 63, w = tid >> 6;
  int col = l & 15, quad = l >> 4;
  const f16* Ag = xh + ((size_t)b * 4096 + m0) * 256;
  const f16* Wg = wh + (size_t)n0 * 256;
  int rloc = l >> 5;   // row within 1KB chunk (2 rows of 512B)
  int l5 = l & 31;     // 16B group within row
#pragma unroll
  for (int p = 0; p < 8; p++) {
    int ci = w * 8 + p;
    int r = ci * 2 + rloc;
    int g = l5 ^ (r & 31);
    gl_lds16(Ag + (size_t)r * 256 + g * 8, smem + ci * 1024);
    gl_lds16(Wg + (size_t)r * 256 + g * 8, smem + 32768 + ci * 1024);
  }
  __syncthreads();
  const char* sA = smem;
  const char* sW = smem + 32768;
  f32x4v acc[4] = {};
  int ar = w * 16 + col;
#pragma unroll
  for (int ks = 0; ks < 8; ks++) {
    int G = ks * 4 + quad;
    f16x8v a = *(const f16x8v*)(sA + ar * 512 + ((G ^ (ar & 31)) * 16));
#pragma unroll
    for (int nt = 0; nt < 4; nt++) {
      int wr = nt * 16 + col;
      f16x8v bb = *(const f16x8v*)(sW + wr * 512 + ((G ^ (wr & 31)) * 16));
      acc[nt] = mfma16(a, bb, acc[nt]);
    }
  }
  bool isqk = (n0 < 256);  // block-uniform
#pragma unroll
  for (int nt = 0; nt < 4; nt++) {
    int o = n0 + nt * 16 + col;
    float bias = bcat[o];
    if (isqk) {
#pragma unroll
      for (int rg = 0; rg < 4; rg++) {
        int i = m0 + w * 16 + quad * 4 + rg;
        qk[((size_t)b * 4096 + i) * 256 + o] = (f16)(acc[nt][rg] + bias);
      }
    } else {
      int i = m0 + w * 16 + quad * 4;
      f16x4v pv;
#pragma unroll
      for (int rg = 0; rg < 4; rg++) pv[rg] = (f16)(acc[nt][rg] + bias);
      *(f16x4v*)&vv[((size_t)b * 256 + (o - 256)) * 4096 + i] = pv;
    }
  }
}

// ---------------- kernel 2: Z partials (no P output) ----------------
// Per block: S for (128 i)x(128 j), K=128 single-shot glds (64KB).
// partial[b][jb][i] = sum over this tile's 128 j of exp2(s_ij).
__global__ void __launch_bounds__(256, 2)
k_sums(const f16* __restrict__ qk, float* __restrict__ partial) {
  extern __shared__ char smem[];   // 64KB: sQ [128 rows][256B] + sK same
  int b = blockIdx.z, i0 = blockIdx.y * 128, j0 = blockIdx.x * 128;
  int tid = threadIdx.x, l = tid & 63, w = tid >> 6;
  int col = l & 15, quad = l >> 4;
  const char* qb = (const char*)(qk + (size_t)b * 4096 * 256);  // rows 512B: q[0,256) k[256,512)
#pragma unroll
  for (int p = 0; p < 8; p++) {
    int ci = w * 8 + p;
    int r = ci * 4 + (l >> 4);
    int g = (l & 15) ^ (r & 15);
    gl_lds16(qb + (size_t)(i0 + r) * 512 + g * 16, smem + ci * 1024);
    gl_lds16(qb + (size_t)(j0 + r) * 512 + 256 + g * 16, smem + 32768 + ci * 1024);
  }
  __syncthreads();
  const char* sQ = smem;
  const char* sK = smem + 32768;
  f32x4v acc[2][8] = {};
#pragma unroll
  for (int ks = 0; ks < 4; ks++) {
    int G = ks * 4 + quad;
    f16x8v a[2];
#pragma unroll
    for (int it = 0; it < 2; it++) {
      int ar = (w * 2 + it) * 16 + col;
      a[it] = *(const f16x8v*)(sQ + ar * 256 + ((G ^ (ar & 15)) * 16));
    }
#pragma unroll
    for (int jt = 0; jt < 8; jt++) {
      int jr = jt * 16 + col;
      f16x8v kb = *(const f16x8v*)(sK + jr * 256 + ((G ^ (jr & 15)) * 16));
#pragma unroll
      for (int it = 0; it < 2; it++)
        acc[it][jt] = mfma16(a[it], kb, acc[it][jt]);
    }
  }
  // Z partial: per (it,rg): sum over 8 j-tiles in-lane, then 16 cols via shuffle
#pragma unroll
  for (int it = 0; it < 2; it++) {
    f32x4v cs;
#pragma unroll
    for (int rg = 0; rg < 4; rg++) {
      float t = 0.f;
#pragma unroll
      for (int jt = 0; jt < 8; jt++) t += exp2f(acc[it][jt][rg]);
#pragma unroll
      for (int d = 1; d < 16; d <<= 1) t += __shfl_xor(t, d, 64);
      cs[rg] = t;
    }
    if (col == 0) {
      size_t base = ((size_t)b * 32 + blockIdx.x) * 4096 + i0 + (w * 2 + it) * 16 + quad * 4;
      *(f32x4v*)&partial[base] = cs;
    }
  }
}

// ---------------- kernel 3a: combine partials -> rowsum ----------------
__global__ void k_rsum(const float* __restrict__ partial, float* __restrict__ rowsum) {
  int b = blockIdx.y;
  int i = blockIdx.x * 256 + threadIdx.x;
  const float* p = partial + (size_t)b * 32 * 4096 + i;
  float s = 0.f;
#pragma unroll 8
  for (int jb = 0; jb < 32; jb++) s += p[(size_t)jb * 4096];
  rowsum[(size_t)b * 4096 + i] = s;
}

// ---------------- kernel 3b: vv(bf16) = vv(f16) / rowsum, in place ----------------
__global__ void k_scalev(u16* __restrict__ vvb, const float* __restrict__ rowsum) {
  size_t idx = ((size_t)blockIdx.x * 256 + threadIdx.x) * 8;
  int i = (int)(idx & 4095);
  int b = (int)(idx >> 20);
  f16x8v v = *(f16x8v*)&vvb[idx];
  const float* rs = rowsum + ((size_t)b << 12) + i;
  u16x8v o;
#pragma unroll
  for (int t = 0; t < 8; t++) o[t] = f2bf((float)v[t] * (1.0f / rs[t]));
  *(u16x8v*)&vvb[idx] = o;
}

// ---------------- kernel 4: fused S-recompute + AV + residual ----------------
// Block: j-tile 64, ALL c (256), loop i in 64-chunks.
// out[b][c][j] = gamma * sum_i vv'[b][c][i] * exp2(s_ij) + x[b][c][j]
// K-frags (this wave's 2 j-tiles) preloaded into registers (no sK in LDS).
// LDS: sQ 16KB (single) + sV 32KB (single) + sP [64][72]bf16 9KB = 57KB.
// Pipeline: q(it+1) glds issued after barrier B (overlaps AV of it);
//           v(it)   glds issued after barrier A (overlaps S-phase of it).
__global__ void __launch_bounds__(512, 1)
k_av2(const f16* __restrict__ qk, const u16* __restrict__ vv,
      const float* __restrict__ x, const float* __restrict__ gamma,
      float* __restrict__ out) {
  extern __shared__ char smem[];  // 58368 B
  char* sQ = smem;                // [64 rows][256 B]
  char* sV = smem + 16384;        // [256 rows][128 B]
  u16*  sP = (u16*)(smem + 49152);// [64 j][72] bf16
  int b = blockIdx.y, j0 = blockIdx.x * 64;
  int tid = threadIdx.x, l = tid & 63, w = tid >> 6;   // 8 waves
  int col = l & 15, quad = l >> 4;
  const char* qb = (const char*)(qk + (size_t)b * 4096 * 256);  // 512B rows
  const char* Vb = (const char*)(vv + (size_t)b * 256 * 4096);  // 8KB rows
  int itile = w >> 1;           // S-phase i-tile (0..3)
  int jsel = (w & 1) * 2;       // S-phase j-tiles {jsel, jsel+1}
  // preload this wave's k-frags into registers (one time, direct global)
  f16x8v kfr[2][4];
#pragma unroll
  for (int e = 0; e < 2; e++)
#pragma unroll
    for (int ks = 0; ks < 4; ks++)
      kfr[e][ks] = *(const f16x8v*)(qb + (size_t)(j0 + (jsel + e) * 16 + col) * 512 +
                                    256 + (ks * 4 + quad) * 16);
  // prologue: stage sQ for i0=0 (16 chunks, 2/wave)
#pragma unroll
  for (int p = 0; p < 2; p++) {
    int ci = w * 2 + p;
    int r = ci * 4 + (l >> 4);
    int g = (l & 15) ^ (r & 15);
    gl_lds16(qb + (size_t)r * 512 + g * 16, sQ + ci * 1024);
  }
  f32x4v acc[2][4] = {};
  for (int it = 0; it < 64; it++) {
    __syncthreads();             // A: sQ(it) staged; prev AV done (sP/sV free)
    {  // stage sV(it): 32 chunks, 4/wave — overlaps S-phase, drained at B
      int i0b = it * 128;        // byte offset of i-chunk in 8KB v-rows
#pragma unroll
      for (int p = 0; p < 4; p++) {
        int ci = w * 4 + p;
        int r = ci * 8 + (l >> 3);
        int g = (l & 7) ^ (r & 7);
        gl_lds16(Vb + (size_t)r * 8192 + i0b + g * 16, sV + ci * 1024);
      }
    }
    // S-phase: this wave's 2 tiles (itile x {jsel,jsel+1}), K=128
    f32x4v s[2] = {};
#pragma unroll
    for (int ks = 0; ks < 4; ks++) {
      int ar = itile * 16 + col;
      f16x8v a = *(const f16x8v*)(sQ + ar * 256 + (((ks * 4 + quad) ^ (ar & 15)) * 16));
#pragma unroll
      for (int e = 0; e < 2; e++) s[e] = mfma16(a, kfr[e][ks], s[e]);
    }
#pragma unroll
    for (int e = 0; e < 2; e++) {
      u16x4v pw;
#pragma unroll
      for (int rg = 0; rg < 4; rg++) pw[rg] = f2bf(exp2f(s[e][rg]));
      *(u16x4v*)&sP[((jsel + e) * 16 + col) * 72 + itile * 16 + quad * 4] = pw;
    }
    __syncthreads();             // B: sP ready; sV(it) staged; sQ free
    if (it < 63) {  // stage sQ(it+1) — overlaps AV, drained at next A
      int i0n = (it + 1) * 64;
#pragma unroll
      for (int p = 0; p < 2; p++) {
        int ci = w * 2 + p;
        int r = ci * 4 + (l >> 4);
        int g = (l & 15) ^ (r & 15);
        gl_lds16(qb + (size_t)(i0n + r) * 512 + g * 16, sQ + ci * 1024);
      }
    }
    // AV: c-tiles {2w, 2w+1} x 4 j-tiles, K=64 (i-chunk)
#pragma unroll
    for (int ks = 0; ks < 2; ks++) {
      s16x8v a[2];
#pragma unroll
      for (int mt = 0; mt < 2; mt++) {
        int cr = (w * 2 + mt) * 16 + col;
        a[mt] = *(const s16x8v*)(sV + cr * 128 + (((ks * 4 + quad) ^ (cr & 7)) * 16));
      }
#pragma unroll
      for (int nt = 0; nt < 4; nt++) {
        s16x8v pb = *(const s16x8v*)((const char*)sP + (nt * 16 + col) * 144 +
                                     (ks * 4 + quad) * 16);
#pragma unroll
        for (int mt = 0; mt < 2; mt++)
          acc[mt][nt] = mfma_bf(a[mt], pb, acc[mt][nt]);
      }
    }
  }
  float g = gamma[0];
#pragma unroll
  for (int mt = 0; mt < 2; mt++)
#pragma unroll
    for (int nt = 0; nt < 4; nt++) {
      int c = (w * 2 + mt) * 16 + quad * 4;
      int j = j0 + nt * 16 + col;
#pragma unroll
      for (int rg = 0; rg < 4; rg++) {
        size_t off = ((size_t)b * 256 + c + rg) * 4096 + j;
        out[off] = g * acc[mt][nt][rg] + x[off];
      }
    }
}

extern "C" void kernel_launch(void* const* d_in, const int* in_sizes, int n_in,
                              void* d_out, int out_size, void* d_ws, size_t ws_size,
                              hipStream_t stream) {
  (void)in_sizes; (void)n_in; (void)out_size; (void)ws_size;
  const float* x  = (const float*)d_in[0];
  const float* wq = (const float*)d_in[1];
  const float* bq = (const float*)d_in[2];
  const float* wk = (const float*)d_in[3];
  const float* bk = (const float*)d_in[4];
  const float* wv = (const float*)d_in[5];
  const float* bv = (const float*)d_in[6];
  const float* gm = (const float*)d_in[7];
  float* out = (float*)d_out;

  char* ws = (char*)d_ws;
  f16*  xh = (f16*)(ws);                      // 8 MB
  f16*  qk = (f16*)(ws + 8388608);            // 8 MB: [b][i][0:128]=q,[128:256]=k
  u16*  vv = (u16*)(ws + 16777216);           // 8 MB: f16 then bf16 in place
  f16*  wh = (f16*)(ws + 25165824);           // 256 KB
  float* bcat    = (float*)(ws + 25427968);   // 2 KB
  float* rowsum  = (float*)(ws + 25430016);   // 64 KB
  float* partial = (float*)(ws + 25495552);   // 2 MB: [b][32][4096]
  // total ~26.4 MB

  hipLaunchKernelGGL(k_wcvt, dim3(512), dim3(256), 0, stream, wq, bq, wk, bk, wv, bv, wh, bcat);
  hipLaunchKernelGGL(k_xsplit, dim3(64, 4, 4), dim3(256), 0, stream, x, xh);
  hipLaunchKernelGGL(k_proj, dim3(8, 64, 4), dim3(256), 65536, stream, xh, wh, bcat, qk, (f16*)vv);
  hipLaunchKernelGGL(k_sums, dim3(32, 32, 4), dim3(256), 65536, stream, qk, partial);
  hipLaunchKernelGGL(k_rsum, dim3(16, 4), dim3(256), 0, stream, partial, rowsum);
  hipLaunchKernelGGL(k_scalev, dim3(2048), dim3(256), 0, stream, vv, rowsum);
  hipLaunchKernelGGL(k_av2, dim3(64, 4), dim3(512), 58368, stream, qk, vv, x, gm, out);
}

// Round 8
// 202.076 us; speedup vs baseline: 1.0630x; 1.0630x over previous
//
#include <hip/hip_runtime.h>
#include <hip/hip_bf16.h>

// ConvSelfAttentionModule: B=4, C=256, CQK=128, N=4096 (64x64), fp32 in/out.
// Pipeline (R8 = R4 proven-good source; only k_pmake occupancy hint changed):
//   k_wcvt   : W -> f16 (no hi/lo split: qk f16 storage rounding dominates error)
//   k_xsplit : transpose x[b][c][n] -> xT[b][n][c] f16
//   k_proj   : f16 MFMA GEMM, K=256 single-shot glds staging -> qk, vv
//   k_pmake  : S tiles (K=128 single-shot glds), P=exp(S) raw bf16 -> P_T[b][j][i],
//              partial column sums. launch_bounds(256,3): LDS 48K*3=147K<=160K,
//              VGPR 68 -> 3 blocks/CU to hide the 135MB write drains (R4 had ~2).
//   k_rsum   : rowsum = sum partials
//   k_scalev : vv bf16 <- f16 vv / rowsum
//   k_av     : bf16 NT GEMM, 128x128 tiles, 512 thr, double-buffered glds
//              (1 barrier/iter, transfer of k+1 overlaps MFMA of k), + residual

typedef _Float16 f16;
typedef _Float16 f16x4v __attribute__((ext_vector_type(4)));
typedef _Float16 f16x8v __attribute__((ext_vector_type(8)));
typedef float f32x4v __attribute__((ext_vector_type(4)));
typedef unsigned short u16;
typedef unsigned short u16x4v __attribute__((ext_vector_type(4)));
typedef unsigned short u16x8v __attribute__((ext_vector_type(8)));
typedef short s16x8v __attribute__((ext_vector_type(8)));

static __device__ __forceinline__ f32x4v mfma16(f16x8v a, f16x8v b, f32x4v c) {
  // D[m][n]: a-frag m=lane&15,k=quad*8+j; b-frag (B^T rows) n=lane&15,k=quad*8+j;
  // D: col(n)=lane&15, row(m)=quad*4+reg
  return __builtin_amdgcn_mfma_f32_16x16x32_f16(a, b, c, 0, 0, 0);
}
static __device__ __forceinline__ f32x4v mfma_bf(s16x8v a, s16x8v b, f32x4v c) {
  return __builtin_amdgcn_mfma_f32_16x16x32_bf16(a, b, c, 0, 0, 0);
}
static __device__ __forceinline__ u16 f2bf(float f) {
  union { __hip_bfloat16 h; u16 u; } cv;
  cv.h = __float2bfloat16(f);  // RNE
  return cv.u;
}

#define AS1q __attribute__((address_space(1)))
#define AS3q __attribute__((address_space(3)))
static __device__ __forceinline__ void gl_lds16(const void* g, void* l) {
  // 16B per lane; LDS dest = wave-uniform base + lane*16 (per-lane global src OK)
  __builtin_amdgcn_global_load_lds((const AS1q unsigned int*)g,
                                   (AS3q unsigned int*)l, 16, 0, 0);
}

// ---------------- kernel 0a: weight convert ----------------
__global__ void k_wcvt(const float* __restrict__ wq, const float* __restrict__ bq,
                       const float* __restrict__ wk, const float* __restrict__ bk,
                       const float* __restrict__ wv, const float* __restrict__ bv,
                       f16* __restrict__ wh, float* __restrict__ bcat) {
  int o = blockIdx.x;          // 512 rows: 0-127 q, 128-255 k, 256-511 v
  int c = threadIdx.x;         // 256
  const float* wrow; float bias;
  if (o < 128)      { wrow = wq + (size_t)o * 256;         bias = bq[o]; }
  else if (o < 256) { wrow = wk + (size_t)(o - 128) * 256; bias = bk[o - 128]; }
  else              { wrow = wv + (size_t)(o - 256) * 256; bias = bv[o - 256]; }
  wh[(size_t)o * 256 + c] = (f16)wrow[c];
  if (c == 0) bcat[o] = bias;
}

// ---------------- kernel 0b: x transpose ----------------
// x[b][c][n] f32 -> xT[b][n][c] f16
__global__ void k_xsplit(const float* __restrict__ x, f16* __restrict__ xh) {
  __shared__ float t[64][65];
  int b = blockIdx.z, c0 = blockIdx.y * 64, n0 = blockIdx.x * 64;
  int tx = threadIdx.x & 63, ty = threadIdx.x >> 6;
  const float* xb = x + ((size_t)b * 256 + c0) * 4096 + n0;
#pragma unroll
  for (int r = ty; r < 64; r += 4) t[r][tx] = xb[(size_t)r * 4096 + tx];
  __syncthreads();
  f16* dh = xh + ((size_t)b * 4096 + n0) * 256 + c0;
#pragma unroll
  for (int r = ty; r < 64; r += 4)
    dh[(size_t)r * 256 + tx] = (f16)t[tx][r];
}

// ---------------- kernel 1: projections (f16 NT GEMM, K=256 single-shot) ----------------
// D[i][o] = sum_c xT[i][c]*W[o][c] + b[o];  o<256 -> qk[b][i][o] ; else vv[b][o-256][i]
// LDS: sA [64 rows][256 f16] 32KB + sW 32KB, XOR-swizzled 16B groups, glds staged.
__global__ void __launch_bounds__(256, 2)
k_proj(const f16* __restrict__ xh, const f16* __restrict__ wh,
       const float* __restrict__ bcat, f16* __restrict__ qk, f16* __restrict__ vv) {
  extern __shared__ char smem[];   // 64KB
  int b = blockIdx.z, m0 = blockIdx.y * 64, n0 = blockIdx.x * 64;
  int tid = threadIdx.x, l = tid & 63, w = tid >> 6;
  int col = l & 15, quad = l >> 4;
  const f16* Ag = xh + ((size_t)b * 4096 + m0) * 256;
  const f16* Wg = wh + (size_t)n0 * 256;
  int rloc = l >> 5;   // row within 1KB chunk (2 rows of 512B)
  int l5 = l & 31;     // 16B group within row
  // stage: 32 chunks A + 32 chunks W; LDS[r][p] = G[r][p ^ (r&31)]
#pragma unroll
  for (int p = 0; p < 8; p++) {
    int ci = w * 8 + p;
    int r = ci * 2 + rloc;
    int g = l5 ^ (r & 31);
    gl_lds16(Ag + (size_t)r * 256 + g * 8, smem + ci * 1024);
    gl_lds16(Wg + (size_t)r * 256 + g * 8, smem + 32768 + ci * 1024);
  }
  __syncthreads();
  const char* sA = smem;
  const char* sW = smem + 32768;
  f32x4v acc[4] = {};
  int ar = w * 16 + col;
#pragma unroll
  for (int ks = 0; ks < 8; ks++) {
    int G = ks * 4 + quad;
    f16x8v a = *(const f16x8v*)(sA + ar * 512 + ((G ^ (ar & 31)) * 16));
#pragma unroll
    for (int nt = 0; nt < 4; nt++) {
      int wr = nt * 16 + col;
      f16x8v bb = *(const f16x8v*)(sW + wr * 512 + ((G ^ (wr & 31)) * 16));
      acc[nt] = mfma16(a, bb, acc[nt]);
    }
  }
  bool isqk = (n0 < 256);  // block-uniform
#pragma unroll
  for (int nt = 0; nt < 4; nt++) {
    int o = n0 + nt * 16 + col;
    float bias = bcat[o];
    if (isqk) {
#pragma unroll
      for (int rg = 0; rg < 4; rg++) {
        int i = m0 + w * 16 + quad * 4 + rg;
        qk[((size_t)b * 4096 + i) * 256 + o] = (f16)(acc[nt][rg] + bias);
      }
    } else {
      int i = m0 + w * 16 + quad * 4;
      f16x4v pv;
#pragma unroll
      for (int rg = 0; rg < 4; rg++) pv[rg] = (f16)(acc[nt][rg] + bias);
      *(f16x4v*)&vv[((size_t)b * 256 + (o - 256)) * 4096 + i] = pv;
    }
  }
}

// ---------------- kernel 2: P^T materialize + partial column sums ----------------
// Per block: S for (128 i) x (64 j), K=128 single-shot via glds.
// P = exp(S) raw (bf16, range-safe) -> LDS transpose -> P_T[b][j][i] coalesced.
// partial[b][jblk][i] = sum over this tile's 64 j of exp(s_ij).
__global__ void __launch_bounds__(256, 3)
k_pmake(const f16* __restrict__ qk, u16* __restrict__ P, float* __restrict__ partial) {
  __shared__ char smem[49152];   // sQ [128][128] (32K) + sK [64][128] (16K)
  f16* sQ = (f16*)smem;
  f16* sK = (f16*)(smem + 32768);
  u16* sPT = (u16*)smem;         // [64][132] overlay after compute
  int b = blockIdx.z, i0 = blockIdx.y * 128, j0 = blockIdx.x * 64;
  int tid = threadIdx.x, l = tid & 63, w = tid >> 6;
  int col = l & 15, q = l >> 4;
  const f16* qb = qk + (size_t)b * 4096 * 256;
#pragma unroll
  for (int p = 0; p < 8; p++) {
    int ci = w * 8 + p;
    int r = ci * 4 + (l >> 4);
    int cb = (l & 15) ^ (r & 15);
    gl_lds16(qb + (size_t)(i0 + r) * 256 + cb * 8, smem + ci * 1024);
  }
#pragma unroll
  for (int p = 0; p < 4; p++) {
    int ci = w * 4 + p;
    int r = ci * 4 + (l >> 4);
    int cb = (l & 15) ^ (r & 15);
    gl_lds16(qb + (size_t)(j0 + r) * 256 + 128 + cb * 8, smem + 32768 + ci * 1024);
  }
  __syncthreads();
  f32x4v acc[2][4] = {};
#pragma unroll
  for (int ks = 0; ks < 4; ks++) {
    int phys = (ks * 4 + q) ^ col;
    f16x8v a[2], bb[4];
#pragma unroll
    for (int mt = 0; mt < 2; mt++)
      a[mt] = *(const f16x8v*)&sQ[(w * 32 + mt * 16 + col) * 128 + phys * 8];
#pragma unroll
    for (int nt = 0; nt < 4; nt++)
      bb[nt] = *(const f16x8v*)&sK[(nt * 16 + col) * 128 + phys * 8];
#pragma unroll
    for (int mt = 0; mt < 2; mt++)
#pragma unroll
      for (int nt = 0; nt < 4; nt++)
        acc[mt][nt] = mfma16(a[mt], bb[nt], acc[mt][nt]);
  }
  float pe[2][4][4];
#pragma unroll
  for (int mt = 0; mt < 2; mt++)
#pragma unroll
    for (int nt = 0; nt < 4; nt++)
#pragma unroll
      for (int rg = 0; rg < 4; rg++)
        pe[mt][nt][rg] = __expf(acc[mt][nt][rg]);
  __syncthreads();  // done with sQ/sK -> reuse as sPT
#pragma unroll
  for (int mt = 0; mt < 2; mt++) {
    int ib = w * 32 + mt * 16 + q * 4;
#pragma unroll
    for (int nt = 0; nt < 4; nt++) {
      u16x4v pw;
#pragma unroll
      for (int rg = 0; rg < 4; rg++) pw[rg] = f2bf(pe[mt][nt][rg]);
      *(u16x4v*)&sPT[(nt * 16 + col) * 132 + ib] = pw;
    }
  }
#pragma unroll
  for (int mt = 0; mt < 2; mt++) {
    f32x4v cs;
#pragma unroll
    for (int rg = 0; rg < 4; rg++) {
      float t = pe[mt][0][rg] + pe[mt][1][rg] + pe[mt][2][rg] + pe[mt][3][rg];
#pragma unroll
      for (int d = 1; d < 16; d <<= 1) t += __shfl_xor(t, d, 64);
      cs[rg] = t;
    }
    if (col == 0) {
      size_t base = ((size_t)b * 64 + blockIdx.x) * 4096 + i0 + w * 32 + mt * 16 + q * 4;
      *(f32x4v*)&partial[base] = cs;
    }
  }
  __syncthreads();
  u16* Pb = P + ((size_t)b * 4096 + j0) * 4096 + i0;
#pragma unroll
  for (int p = 0; p < 4; p++) {
    int slot = p * 256 + tid;
    int jr = slot >> 4, c16 = slot & 15;
    *(u16x8v*)&Pb[(size_t)jr * 4096 + c16 * 8] =
        *(const u16x8v*)&sPT[jr * 132 + c16 * 8];
  }
}

// ---------------- kernel 3a: combine partials -> rowsum ----------------
__global__ void k_rsum(const float* __restrict__ partial, float* __restrict__ rowsum) {
  int b = blockIdx.y;
  int i = blockIdx.x * 256 + threadIdx.x;
  const float* p = partial + (size_t)b * 64 * 4096 + i;
  float s = 0.f;
#pragma unroll 8
  for (int jb = 0; jb < 64; jb++) s += p[(size_t)jb * 4096];
  rowsum[(size_t)b * 4096 + i] = s;
}

// ---------------- kernel 3b: vv(bf16) = vv(f16) / rowsum, in place ----------------
__global__ void k_scalev(u16* __restrict__ vvb, const float* __restrict__ rowsum) {
  size_t idx = ((size_t)blockIdx.x * 256 + threadIdx.x) * 8;
  int i = (int)(idx & 4095);
  int b = (int)(idx >> 20);
  f16x8v v = *(f16x8v*)&vvb[idx];
  const float* rs = rowsum + ((size_t)b << 12) + i;
  u16x8v o;
#pragma unroll
  for (int t = 0; t < 8; t++) o[t] = f2bf((float)v[t] * (1.0f / rs[t]));
  *(u16x8v*)&vvb[idx] = o;
}

// ---------------- kernel 4: AV GEMM (bf16), 128x128 tile, dbuf pipeline ----------------
// out[b][c][j] = gamma * sum_i vv'[b][c][i] * P_T[b][j][i] + x[b][c][j]
// 512 threads (8 waves: cw=w>>2 over 2x64 c, jw=w&3 over 4x32 j). BK=64.
// LDS 2 x (A 16KB | B 16KB); one __syncthreads per iter; glds of tile k+1
// issued after the barrier overlaps MFMA of tile k.
__global__ void __launch_bounds__(512, 2)
k_av(const u16* __restrict__ vv, const u16* __restrict__ P,
     const float* __restrict__ x, const float* __restrict__ gamma,
     float* __restrict__ out) {
  extern __shared__ char smem[];  // 64KB
  int b = blockIdx.z, c0 = blockIdx.x * 128, j0 = blockIdx.y * 128;
  int tid = threadIdx.x, l = tid & 63, w = tid >> 6;
  int col = l & 15, q = l >> 4;
  int cw = w >> 2, jw = w & 3;
  const u16* Ab = vv + ((size_t)b * 256 + c0) * 4096;
  const u16* Bb = P + ((size_t)b * 4096 + j0) * 4096;
  int rloc = l >> 3;   // row within 1KB chunk (8 rows of 128B)
  int gsw = l & 7;     // 16B group within row
  f32x4v acc[4][2] = {};
  // prologue: stage tile 0 into buf 0
#pragma unroll
  for (int p = 0; p < 4; p++) {
    int ci = w * 4 + p;                       // 0..15 A rows, 16..31 B rows
    int rr = (ci & 15) * 8 + rloc;
    int g = gsw ^ (rr & 7);
    const u16* src = (ci < 16 ? Ab : Bb) + (size_t)rr * 4096 + g * 8;
    gl_lds16(src, smem + ci * 1024);
  }
  for (int it = 0; it < 64; it++) {
    __syncthreads();   // drains glds of current buf (vmcnt) + prev reads
    if (it < 63) {
      int k0 = (it + 1) * 64;
      char* nb = smem + ((it + 1) & 1) * 32768;
#pragma unroll
      for (int p = 0; p < 4; p++) {
        int ci = w * 4 + p;
        int rr = (ci & 15) * 8 + rloc;
        int g = gsw ^ (rr & 7);
        const u16* src = (ci < 16 ? Ab : Bb) + (size_t)rr * 4096 + k0 + g * 8;
        gl_lds16(src, nb + ci * 1024);
      }
    }
    const char* cur = smem + (it & 1) * 32768;
#pragma unroll
    for (int ks = 0; ks < 2; ks++) {
      int G = ks * 4 + q;
      s16x8v a[4], bb[2];
#pragma unroll
      for (int mt = 0; mt < 4; mt++) {
        int ar = cw * 64 + mt * 16 + col;
        a[mt] = *(const s16x8v*)(cur + ar * 128 + ((G ^ (ar & 7)) * 16));
      }
#pragma unroll
      for (int nt = 0; nt < 2; nt++) {
        int jr = jw * 32 + nt * 16 + col;
        bb[nt] = *(const s16x8v*)(cur + 16384 + jr * 128 + ((G ^ (jr & 7)) * 16));
      }
#pragma unroll
      for (int mt = 0; mt < 4; mt++)
#pragma unroll
        for (int nt = 0; nt < 2; nt++)
          acc[mt][nt] = mfma_bf(a[mt], bb[nt], acc[mt][nt]);
    }
  }
  float g = gamma[0];
#pragma unroll
  for (int mt = 0; mt < 4; mt++)
#pragma unroll
    for (int nt = 0; nt < 2; nt++) {
      int c = c0 + cw * 64 + mt * 16 + q * 4;
      int j = j0 + jw * 32 + nt * 16 + col;
#pragma unroll
      for (int rg = 0; rg < 4; rg++) {
        size_t off = ((size_t)b * 256 + c + rg) * 4096 + j;
        out[off] = g * acc[mt][nt][rg] + x[off];
      }
    }
}

extern "C" void kernel_launch(void* const* d_in, const int* in_sizes, int n_in,
                              void* d_out, int out_size, void* d_ws, size_t ws_size,
                              hipStream_t stream) {
  (void)in_sizes; (void)n_in; (void)out_size; (void)ws_size;
  const float* x  = (const float*)d_in[0];
  const float* wq = (const float*)d_in[1];
  const float* bq = (const float*)d_in[2];
  const float* wk = (const float*)d_in[3];
  const float* bk = (const float*)d_in[4];
  const float* wv = (const float*)d_in[5];
  const float* bv = (const float*)d_in[6];
  const float* gm = (const float*)d_in[7];
  float* out = (float*)d_out;

  char* ws = (char*)d_ws;
  // P (128 MB) overlaps xh lifetime (xh dead after k_proj). Peak ~148.3 MB.
  const size_t P_BYTES = (size_t)4 * 4096 * 4096 * 2;
  u16*  Pt = (u16*)(ws);
  f16*  xh = (f16*)(ws);                     // 8 MB, dies before Pt written
  char* tail = ws + P_BYTES;
  f16*  qk = (f16*)(tail);                   // 8 MB: [b][i][0:128]=q,[128:256]=k
  u16*  vv = (u16*)(tail + 8388608);         // 8 MB: f16 then bf16 in place
  f16*  wh = (f16*)(tail + 16777216);        // 256 KB
  float* bcat    = (float*)(tail + 17039360);
  float* rowsum  = (float*)(tail + 17041408);
  float* partial = (float*)(tail + 17106944); // 4 MB: [b][64][4096]

  hipLaunchKernelGGL(k_wcvt, dim3(512), dim3(256), 0, stream, wq, bq, wk, bk, wv, bv, wh, bcat);
  hipLaunchKernelGGL(k_xsplit, dim3(64, 4, 4), dim3(256), 0, stream, x, xh);
  hipLaunchKernelGGL(k_proj, dim3(8, 64, 4), dim3(256), 65536, stream, xh, wh, bcat, qk, (f16*)vv);
  hipLaunchKernelGGL(k_pmake, dim3(64, 32, 4), dim3(256), 0, stream, qk, Pt, partial);
  hipLaunchKernelGGL(k_rsum, dim3(16, 4), dim3(256), 0, stream, partial, rowsum);
  hipLaunchKernelGGL(k_scalev, dim3(2048), dim3(256), 0, stream, vv, rowsum);
  hipLaunchKernelGGL(k_av, dim3(2, 32, 4), dim3(512), 65536, stream, vv, Pt, x, gm, out);
}